// Round 1
// baseline (379.286 us; speedup 1.0000x reference)
//
#include <hip/hip_runtime.h>
#include <hip/hip_bf16.h>

// Problem constants (from reference setup_inputs)
#define DEG        16
#define IN_FEATS   256
#define NUM_HEADS  4
#define OUT_FEATS  64
#define HF         (NUM_HEADS * OUT_FEATS)   // 256
#define NEG_SLOPE  0.2f

// ---------------------------------------------------------------------------
// Kernel 1: h = feat @ W   (M x 256) * (256 x 256), fp32 vector-ALU tiled GEMM
// 64x64 block tile, BK=64, 256 threads, 4x4 micro-tile per thread.
// ---------------------------------------------------------------------------
__global__ __launch_bounds__(256) void gat_gemm(
    const float* __restrict__ A,   // feat [M,256]
    const float* __restrict__ B,   // W    [256,256]
    float* __restrict__ C,         // h    [M,256]
    int M)
{
    __shared__ float As[64][65];
    __shared__ float Bs[64][65];

    const int tid = threadIdx.x;
    const int tx = tid & 15;        // 0..15
    const int ty = tid >> 4;        // 0..15
    const int rowBase = blockIdx.x * 64;
    const int colBase = blockIdx.y * 64;

    float acc[4][4] = {{0.f}};

    for (int kt = 0; kt < IN_FEATS; kt += 64) {
        // Cooperative load: 64x64 tile of A and of B, float4 per thread x4
        #pragma unroll
        for (int i = 0; i < 4; ++i) {
            int idx = tid + 256 * i;          // 0..1023
            int r   = idx >> 4;               // 0..63
            int c4  = (idx & 15) << 2;        // 0,4,...,60
            int gr  = rowBase + r;
            float4 va;
            if (gr < M) va = *(const float4*)&A[(size_t)gr * IN_FEATS + kt + c4];
            else        va = make_float4(0.f, 0.f, 0.f, 0.f);
            As[r][c4 + 0] = va.x; As[r][c4 + 1] = va.y;
            As[r][c4 + 2] = va.z; As[r][c4 + 3] = va.w;

            float4 vb = *(const float4*)&B[(size_t)(kt + r) * HF + colBase + c4];
            Bs[r][c4 + 0] = vb.x; Bs[r][c4 + 1] = vb.y;
            Bs[r][c4 + 2] = vb.z; Bs[r][c4 + 3] = vb.w;
        }
        __syncthreads();

        #pragma unroll
        for (int kk = 0; kk < 64; ++kk) {
            float a[4], b[4];
            #pragma unroll
            for (int i = 0; i < 4; ++i) a[i] = As[ty * 4 + i][kk];
            #pragma unroll
            for (int j = 0; j < 4; ++j) b[j] = Bs[kk][tx * 4 + j];
            #pragma unroll
            for (int i = 0; i < 4; ++i)
                #pragma unroll
                for (int j = 0; j < 4; ++j)
                    acc[i][j] = fmaf(a[i], b[j], acc[i][j]);
        }
        __syncthreads();
    }

    #pragma unroll
    for (int i = 0; i < 4; ++i) {
        int gr = rowBase + ty * 4 + i;
        if (gr < M) {
            #pragma unroll
            for (int j = 0; j < 4; ++j)
                C[(size_t)gr * HF + colBase + tx * 4 + j] = acc[i][j];
        }
    }
}

// ---------------------------------------------------------------------------
// Kernel 2: attn_row[n,hd] = sum_f h[n,hd,f]*attn_l[hd,f];  same for attn_col.
// One block (256 thr) per node; each wave handles one head (64 feats).
// ---------------------------------------------------------------------------
__global__ __launch_bounds__(256) void gat_scores(
    const float* __restrict__ h,        // [N, 256]
    const float* __restrict__ attn_l,   // [256]
    const float* __restrict__ attn_r,   // [256]
    float* __restrict__ arow,           // [N,4]
    float* __restrict__ acol,           // [N,4]
    int N)
{
    const int n = blockIdx.x;
    if (n >= N) return;
    const int tid = threadIdx.x;

    float v  = h[(size_t)n * HF + tid];
    float sl = v * attn_l[tid];
    float sr = v * attn_r[tid];

    #pragma unroll
    for (int off = 32; off >= 1; off >>= 1) {
        sl += __shfl_xor(sl, off, 64);
        sr += __shfl_xor(sr, off, 64);
    }
    if ((tid & 63) == 0) {
        int hd = tid >> 6;
        arow[n * NUM_HEADS + hd] = sl;
        acol[n * NUM_HEADS + hd] = sr;
    }
}

// ---------------------------------------------------------------------------
// Kernel 3: per-dst-node softmax over 16 neighbors + weighted aggregation.
// One block per node; wave w = head w; lane = output feature.
// Edge scores replicated into each 16-lane group; width-16 shuffle softmax;
// 16-iter gather-FMA with wave-broadcast alpha/src. No LDS, no barriers.
// ---------------------------------------------------------------------------
__global__ __launch_bounds__(256) void gat_aggregate(
    const float* __restrict__ h,        // [N, 256]
    const float* __restrict__ arow,     // [N,4]
    const float* __restrict__ acol,     // [N,4]
    const int* __restrict__ col_ind,    // [N*16]
    float* __restrict__ out,            // [N, 256]
    int N)
{
    const int n = blockIdx.x;
    if (n >= N) return;
    const int tid  = threadIdx.x;
    const int hd   = tid >> 6;          // head (one per wave)
    const int lane = tid & 63;
    const int j16  = lane & 15;

    // Each lane holds edge j16's src and score (4 replicated groups per wave)
    int   src = col_ind[n * DEG + j16];
    float e   = arow[n * NUM_HEADS + hd] + acol[src * NUM_HEADS + hd];
    e = (e > 0.f) ? e : NEG_SLOPE * e;

    // width-16 max
    float m = e;
    #pragma unroll
    for (int off = 8; off >= 1; off >>= 1)
        m = fmaxf(m, __shfl_xor(m, off, 16));
    float ex = __expf(e - m);
    float s = ex;
    #pragma unroll
    for (int off = 8; off >= 1; off >>= 1)
        s += __shfl_xor(s, off, 16);
    float alpha = ex / s;

    // Gather-accumulate: wave reads h[src, hd, lane] (256B coalesced per wave)
    float acc = 0.f;
    const float* hb = h + hd * OUT_FEATS + lane;
    #pragma unroll
    for (int j = 0; j < DEG; ++j) {
        float a  = __shfl(alpha, j, 64);   // lane j holds edge j's alpha
        int   sj = __shfl(src,   j, 64);
        acc = fmaf(a, hb[(size_t)sj * HF], acc);
    }
    out[(size_t)n * HF + hd * OUT_FEATS + lane] = acc;
}

// ---------------------------------------------------------------------------
extern "C" void kernel_launch(void* const* d_in, const int* in_sizes, int n_in,
                              void* d_out, int out_size, void* d_ws, size_t ws_size,
                              hipStream_t stream) {
    // Input order: row_ptr, col_ind, col_ptr, row_ind, feat, W, attn_l, attn_r
    const int*   col_ind = (const int*)  d_in[1];
    const float* feat    = (const float*)d_in[4];
    const float* W       = (const float*)d_in[5];
    const float* attn_l  = (const float*)d_in[6];
    const float* attn_r  = (const float*)d_in[7];
    float* out = (float*)d_out;

    const int N = in_sizes[0] - 1;      // 50000 nodes

    // Workspace layout: h [N*256] | arow [N*4] | acol [N*4]
    float* h    = (float*)d_ws;
    float* arow = h + (size_t)N * HF;
    float* acol = arow + (size_t)N * NUM_HEADS;

    // 1) projection
    dim3 ggrid((N + 63) / 64, HF / 64);
    gat_gemm<<<ggrid, 256, 0, stream>>>(feat, W, h, N);

    // 2) per-node attention scores
    gat_scores<<<N, 256, 0, stream>>>(h, attn_l, attn_r, arow, acol, N);

    // 3) softmax + aggregate
    gat_aggregate<<<N, 256, 0, stream>>>(h, arow, acol, col_ind, out, N);
}

// Round 2
// 239.969 us; speedup vs baseline: 1.5806x; 1.5806x over previous
//
#include <hip/hip_runtime.h>
#include <hip/hip_bf16.h>

#define DEG        16
#define IN_FEATS   256
#define NUM_HEADS  4
#define OUT_FEATS  64
#define HF         256
#define NEG_SLOPE  0.2f

#define BM 64
#define BK 64
#define APITCH 72      // 64 + 8 bf16, keeps 16B alignment (144 B rows)
#define BPITCH 72
#define CPITCH 264     // 256 + 8

typedef __attribute__((ext_vector_type(8))) short  short8;
typedef __attribute__((ext_vector_type(4))) float  floatx4;

__device__ __forceinline__ unsigned short f2bf(float f) {
    union { float f; unsigned u; } v; v.f = f;
    unsigned r = v.u + 0x7fffu + ((v.u >> 16) & 1u);   // round-to-nearest-even
    return (unsigned short)(r >> 16);
}
__device__ __forceinline__ float bf2f(unsigned short u) {
    union { unsigned u; float f; } v; v.u = ((unsigned)u) << 16;
    return v.f;
}

// ---------------------------------------------------------------------------
// Kernel 0: Wt[n][k] = bf16(W[k][n])  (256x256, tiny)
// ---------------------------------------------------------------------------
__global__ __launch_bounds__(256) void conv_wt(
    const float* __restrict__ W, unsigned short* __restrict__ Wt)
{
    int n = blockIdx.x;
    int k = threadIdx.x;
    Wt[n * 256 + k] = f2bf(W[k * 256 + n]);
}

// ---------------------------------------------------------------------------
// Kernel 1: h = feat @ W via MFMA bf16, tile 64x256 (full width), BK=64.
// Epilogue fuses: (a) arow/acol attention scores (wave w == head w),
// (b) bf16 h store via LDS transpose for coalescing.
// ---------------------------------------------------------------------------
__global__ __launch_bounds__(256, 3) void gat_gemm_mfma(
    const float* __restrict__ A,              // feat [M,256] fp32
    const unsigned short* __restrict__ Bt,    // Wt bf16 [n=256][k=256]
    const float* __restrict__ attn_l,         // [256]
    const float* __restrict__ attn_r,         // [256]
    unsigned short* __restrict__ Hb,          // h bf16 [M,256]
    float* __restrict__ arow,                 // [M,4]
    float* __restrict__ acol,                 // [M,4]
    int M)
{
    // As: 64x72 bf16 (9216 B) | Bs: 256x72 bf16 (36864 B)  -> 46080 B
    // Cs (reuses whole buffer): 64x264 bf16 (33792 B)
    __shared__ __align__(16) unsigned short SMEM[BM * APITCH + 256 * BPITCH];
    unsigned short* As = SMEM;
    unsigned short* Bs = SMEM + BM * APITCH;
    unsigned short* Cs = SMEM;

    const int tid  = threadIdx.x;
    const int wave = tid >> 6;       // == head
    const int lane = tid & 63;
    const int l15  = lane & 15;
    const int quad = lane >> 4;
    const int rowBase = blockIdx.x * BM;

    floatx4 acc[4][4] = {};

    for (int kt = 0; kt < IN_FEATS; kt += BK) {
        // Stage A: 64 rows x 64 k fp32 -> bf16   (1024 float4s, 4/thread)
        #pragma unroll
        for (int i = 0; i < 4; ++i) {
            int f  = tid + 256 * i;
            int r  = f >> 4;                 // 16 float4 per row
            int c4 = (f & 15) << 2;
            int gr = rowBase + r;
            float4 va = (gr < M) ? *(const float4*)&A[(size_t)gr * IN_FEATS + kt + c4]
                                 : make_float4(0.f, 0.f, 0.f, 0.f);
            ushort4 pb;
            pb.x = f2bf(va.x); pb.y = f2bf(va.y);
            pb.z = f2bf(va.z); pb.w = f2bf(va.w);
            *(ushort4*)&As[r * APITCH + c4] = pb;
        }
        // Stage B: 256 n-rows x 64 k bf16        (2048 16B chunks, 8/thread)
        #pragma unroll
        for (int i = 0; i < 8; ++i) {
            int f  = tid + 256 * i;
            int n  = f >> 3;                 // 8 chunks per row
            int k8 = (f & 7) << 3;
            uint4 v = *(const uint4*)&Bt[n * 256 + kt + k8];
            *(uint4*)&Bs[n * BPITCH + k8] = v;
        }
        __syncthreads();

        #pragma unroll
        for (int k0 = 0; k0 < BK; k0 += 32) {
            short8 af[4], bfr[4];
            #pragma unroll
            for (int mi = 0; mi < 4; ++mi)
                af[mi] = *(const short8*)&As[(mi * 16 + l15) * APITCH + k0 + quad * 8];
            #pragma unroll
            for (int ni = 0; ni < 4; ++ni)
                bfr[ni] = *(const short8*)&Bs[(wave * 64 + ni * 16 + l15) * BPITCH + k0 + quad * 8];
            #pragma unroll
            for (int mi = 0; mi < 4; ++mi)
                #pragma unroll
                for (int ni = 0; ni < 4; ++ni)
                    acc[mi][ni] = __builtin_amdgcn_mfma_f32_16x16x32_bf16(
                        af[mi], bfr[ni], acc[mi][ni], 0, 0, 0);
        }
        __syncthreads();
    }

    // ---- Epilogue A: attention scores. Wave w holds cols w*64..w*64+63 == head w.
    // C/D layout: col = ni*16 + l15, row = mi*16 + quad*4 + reg.
    float al[4], ar[4];
    #pragma unroll
    for (int ni = 0; ni < 4; ++ni) {
        al[ni] = attn_l[wave * 64 + ni * 16 + l15];
        ar[ni] = attn_r[wave * 64 + ni * 16 + l15];
    }
    #pragma unroll
    for (int mi = 0; mi < 4; ++mi) {
        #pragma unroll
        for (int reg = 0; reg < 4; ++reg) {
            float pl = 0.f, pr = 0.f;
            #pragma unroll
            for (int ni = 0; ni < 4; ++ni) {
                pl = fmaf(acc[mi][ni][reg], al[ni], pl);
                pr = fmaf(acc[mi][ni][reg], ar[ni], pr);
            }
            #pragma unroll
            for (int off = 8; off >= 1; off >>= 1) {
                pl += __shfl_xor(pl, off, 64);   // stays within 16-lane quad
                pr += __shfl_xor(pr, off, 64);
            }
            if (l15 == 0) {
                int gr = rowBase + mi * 16 + quad * 4 + reg;
                if (gr < M) {
                    arow[gr * NUM_HEADS + wave] = pl;
                    acol[gr * NUM_HEADS + wave] = pr;
                }
            }
        }
    }

    // ---- Epilogue B: h -> bf16, coalesced store via LDS transpose.
    #pragma unroll
    for (int mi = 0; mi < 4; ++mi)
        #pragma unroll
        for (int ni = 0; ni < 4; ++ni)
            #pragma unroll
            for (int reg = 0; reg < 4; ++reg)
                Cs[(mi * 16 + quad * 4 + reg) * CPITCH + wave * 64 + ni * 16 + l15] =
                    f2bf(acc[mi][ni][reg]);
    __syncthreads();

    // 64 rows x 256 bf16 = 2048 16B chunks, 8 per thread
    #pragma unroll
    for (int i = 0; i < 8; ++i) {
        int f  = tid + 256 * i;
        int r  = f >> 5;                    // 32 chunks per row
        int c8 = (f & 31) << 3;
        int gr = rowBase + r;
        if (gr < M) {
            uint4 v = *(const uint4*)&Cs[r * CPITCH + c8];
            *(uint4*)&Hb[(size_t)gr * HF + c8] = v;
        }
    }
}

// ---------------------------------------------------------------------------
// Kernel 2: per-dst softmax over 16 neighbors + weighted gather (bf16 h).
// One block per node; wave = head; lane = feature. No LDS, no barriers.
// ---------------------------------------------------------------------------
__global__ __launch_bounds__(256) void gat_aggregate(
    const unsigned short* __restrict__ Hb,   // bf16 [N,256]
    const float* __restrict__ arow,          // [N,4]
    const float* __restrict__ acol,          // [N,4]
    const int* __restrict__ col_ind,         // [N*16]
    float* __restrict__ out,                 // [N,256] fp32
    int N)
{
    const int n = blockIdx.x;
    if (n >= N) return;
    const int tid  = threadIdx.x;
    const int hd   = tid >> 6;
    const int lane = tid & 63;
    const int j16  = lane & 15;

    int   src = col_ind[n * DEG + j16];
    float e   = arow[n * NUM_HEADS + hd] + acol[src * NUM_HEADS + hd];
    e = (e > 0.f) ? e : NEG_SLOPE * e;

    float m = e;
    #pragma unroll
    for (int off = 8; off >= 1; off >>= 1)
        m = fmaxf(m, __shfl_xor(m, off, 16));
    float ex = __expf(e - m);
    float s = ex;
    #pragma unroll
    for (int off = 8; off >= 1; off >>= 1)
        s += __shfl_xor(s, off, 16);
    float alpha = ex / s;

    float acc = 0.f;
    const unsigned short* hb = Hb + hd * OUT_FEATS + lane;
    #pragma unroll
    for (int j = 0; j < DEG; ++j) {
        float a  = __shfl(alpha, j, 64);
        int   sj = __shfl(src,   j, 64);
        acc = fmaf(a, bf2f(hb[(size_t)sj * HF]), acc);
    }
    out[(size_t)n * HF + hd * OUT_FEATS + lane] = acc;
}

// ---------------------------------------------------------------------------
extern "C" void kernel_launch(void* const* d_in, const int* in_sizes, int n_in,
                              void* d_out, int out_size, void* d_ws, size_t ws_size,
                              hipStream_t stream) {
    // Inputs: row_ptr, col_ind, col_ptr, row_ind, feat, W, attn_l, attn_r
    const int*   col_ind = (const int*)  d_in[1];
    const float* feat    = (const float*)d_in[4];
    const float* W       = (const float*)d_in[5];
    const float* attn_l  = (const float*)d_in[6];
    const float* attn_r  = (const float*)d_in[7];
    float* out = (float*)d_out;

    const int N = in_sizes[0] - 1;   // 50000

    // Workspace: Hb bf16 [N*256] | arow f32 [N*4] | acol f32 [N*4] | Wt bf16 [64K]
    unsigned short* Hb = (unsigned short*)d_ws;
    float* arow = (float*)(Hb + (size_t)N * HF);
    float* acol = arow + (size_t)N * NUM_HEADS;
    unsigned short* Wt = (unsigned short*)(acol + (size_t)N * NUM_HEADS);

    conv_wt<<<256, 256, 0, stream>>>(W, Wt);

    dim3 ggrid((N + BM - 1) / BM);
    gat_gemm_mfma<<<ggrid, 256, 0, stream>>>(feat, Wt, attn_l, attn_r,
                                             Hb, arow, acol, N);

    gat_aggregate<<<N, 256, 0, stream>>>(Hb, arow, acol, col_ind, out, N);
}

// Round 3
// 215.781 us; speedup vs baseline: 1.7577x; 1.1121x over previous
//
#include <hip/hip_runtime.h>
#include <hip/hip_bf16.h>

#define DEG        16
#define IN_FEATS   256
#define NUM_HEADS  4
#define OUT_FEATS  64
#define HF         256
#define NEG_SLOPE  0.2f

#define BM 64
#define BK 64
#define APITCH 72      // 64 + 8 bf16, keeps 16B alignment (144 B rows)
#define BPITCH 72
#define CPITCH 264     // 256 + 8

typedef __attribute__((ext_vector_type(8))) short  short8;
typedef __attribute__((ext_vector_type(4))) float  floatx4;

__device__ __forceinline__ unsigned short f2bf(float f) {
    union { float f; unsigned u; } v; v.f = f;
    unsigned r = v.u + 0x7fffu + ((v.u >> 16) & 1u);   // round-to-nearest-even
    return (unsigned short)(r >> 16);
}
__device__ __forceinline__ float bf2f(unsigned short u) {
    union { unsigned u; float f; } v; v.u = ((unsigned)u) << 16;
    return v.f;
}

// ---------------------------------------------------------------------------
// Kernel 0: Wt[n][k] = bf16(W[k][n])  (256x256, tiny)
// ---------------------------------------------------------------------------
__global__ __launch_bounds__(256) void conv_wt(
    const float* __restrict__ W, unsigned short* __restrict__ Wt)
{
    int n = blockIdx.x;
    int k = threadIdx.x;
    Wt[n * 256 + k] = f2bf(W[k * 256 + n]);
}

// ---------------------------------------------------------------------------
// Kernel 1: h = feat @ W via MFMA bf16, tile 64x256 (full width), BK=64.
// Epilogue fuses: (a) arow/acol attention scores (wave w == head w),
// (b) bf16 h store via LDS transpose for coalescing.  (unchanged, known-good)
// ---------------------------------------------------------------------------
__global__ __launch_bounds__(256, 3) void gat_gemm_mfma(
    const float* __restrict__ A,              // feat [M,256] fp32
    const unsigned short* __restrict__ Bt,    // Wt bf16 [n=256][k=256]
    const float* __restrict__ attn_l,         // [256]
    const float* __restrict__ attn_r,         // [256]
    unsigned short* __restrict__ Hb,          // h bf16 [M,256]
    float* __restrict__ arow,                 // [M,4]
    float* __restrict__ acol,                 // [M,4]
    int M)
{
    __shared__ __align__(16) unsigned short SMEM[BM * APITCH + 256 * BPITCH];
    unsigned short* As = SMEM;
    unsigned short* Bs = SMEM + BM * APITCH;
    unsigned short* Cs = SMEM;

    const int tid  = threadIdx.x;
    const int wave = tid >> 6;       // == head
    const int lane = tid & 63;
    const int l15  = lane & 15;
    const int quad = lane >> 4;
    const int rowBase = blockIdx.x * BM;

    floatx4 acc[4][4] = {};

    for (int kt = 0; kt < IN_FEATS; kt += BK) {
        #pragma unroll
        for (int i = 0; i < 4; ++i) {
            int f  = tid + 256 * i;
            int r  = f >> 4;
            int c4 = (f & 15) << 2;
            int gr = rowBase + r;
            float4 va = (gr < M) ? *(const float4*)&A[(size_t)gr * IN_FEATS + kt + c4]
                                 : make_float4(0.f, 0.f, 0.f, 0.f);
            ushort4 pb;
            pb.x = f2bf(va.x); pb.y = f2bf(va.y);
            pb.z = f2bf(va.z); pb.w = f2bf(va.w);
            *(ushort4*)&As[r * APITCH + c4] = pb;
        }
        #pragma unroll
        for (int i = 0; i < 8; ++i) {
            int f  = tid + 256 * i;
            int n  = f >> 3;
            int k8 = (f & 7) << 3;
            uint4 v = *(const uint4*)&Bt[n * 256 + kt + k8];
            *(uint4*)&Bs[n * BPITCH + k8] = v;
        }
        __syncthreads();

        #pragma unroll
        for (int k0 = 0; k0 < BK; k0 += 32) {
            short8 af[4], bfr[4];
            #pragma unroll
            for (int mi = 0; mi < 4; ++mi)
                af[mi] = *(const short8*)&As[(mi * 16 + l15) * APITCH + k0 + quad * 8];
            #pragma unroll
            for (int ni = 0; ni < 4; ++ni)
                bfr[ni] = *(const short8*)&Bs[(wave * 64 + ni * 16 + l15) * BPITCH + k0 + quad * 8];
            #pragma unroll
            for (int mi = 0; mi < 4; ++mi)
                #pragma unroll
                for (int ni = 0; ni < 4; ++ni)
                    acc[mi][ni] = __builtin_amdgcn_mfma_f32_16x16x32_bf16(
                        af[mi], bfr[ni], acc[mi][ni], 0, 0, 0);
        }
        __syncthreads();
    }

    // ---- Epilogue A: attention scores (wave == head).
    float al[4], ar[4];
    #pragma unroll
    for (int ni = 0; ni < 4; ++ni) {
        al[ni] = attn_l[wave * 64 + ni * 16 + l15];
        ar[ni] = attn_r[wave * 64 + ni * 16 + l15];
    }
    #pragma unroll
    for (int mi = 0; mi < 4; ++mi) {
        #pragma unroll
        for (int reg = 0; reg < 4; ++reg) {
            float pl = 0.f, pr = 0.f;
            #pragma unroll
            for (int ni = 0; ni < 4; ++ni) {
                pl = fmaf(acc[mi][ni][reg], al[ni], pl);
                pr = fmaf(acc[mi][ni][reg], ar[ni], pr);
            }
            #pragma unroll
            for (int off = 8; off >= 1; off >>= 1) {
                pl += __shfl_xor(pl, off, 64);
                pr += __shfl_xor(pr, off, 64);
            }
            if (l15 == 0) {
                int gr = rowBase + mi * 16 + quad * 4 + reg;
                if (gr < M) {
                    arow[gr * NUM_HEADS + wave] = pl;
                    acol[gr * NUM_HEADS + wave] = pr;
                }
            }
        }
    }

    // ---- Epilogue B: h -> bf16, coalesced store via LDS transpose.
    #pragma unroll
    for (int mi = 0; mi < 4; ++mi)
        #pragma unroll
        for (int ni = 0; ni < 4; ++ni)
            #pragma unroll
            for (int reg = 0; reg < 4; ++reg)
                Cs[(mi * 16 + quad * 4 + reg) * CPITCH + wave * 64 + ni * 16 + l15] =
                    f2bf(acc[mi][ni][reg]);
    __syncthreads();

    #pragma unroll
    for (int i = 0; i < 8; ++i) {
        int f  = tid + 256 * i;
        int r  = f >> 5;
        int c8 = (f & 31) << 3;
        int gr = rowBase + r;
        if (gr < M) {
            uint4 v = *(const uint4*)&Cs[r * CPITCH + c8];
            *(uint4*)&Hb[(size_t)gr * HF + c8] = v;
        }
    }
}

// ---------------------------------------------------------------------------
// Kernel 2 (v2): per-dst softmax + gather, full-row 8B/lane loads.
// One block per node. Each wave redundantly computes all 16x4 edge alphas
// (lane = head*16 + edge), then gathers FULL 512B rows of 4 of the 16 edges
// (uint2 = 4 bf16 per lane -> one 512B transaction per edge). Cross-wave
// combine via 4KB LDS. 4x fewer gather transactions than 2B/lane version.
// ---------------------------------------------------------------------------
__global__ __launch_bounds__(256) void gat_aggregate2(
    const unsigned short* __restrict__ Hb,   // bf16 [N,256]
    const float* __restrict__ arow,          // [N,4]
    const float* __restrict__ acol,          // [N,4]
    const int* __restrict__ col_ind,         // [N*16]
    float* __restrict__ out,                 // [N,256] fp32
    int N)
{
    __shared__ float red[4][256];

    const int n = blockIdx.x;
    const int tid  = threadIdx.x;
    const int wave = tid >> 6;
    const int lane = tid & 63;
    const int j16  = lane & 15;      // edge index for score phase
    const int hd16 = lane >> 4;      // head index for score phase

    // ---- Phase 1: scores. Lane (hd16, j16) computes e[edge=j16][head=hd16].
    int   src_e = col_ind[n * DEG + j16];
    float e = arow[n * NUM_HEADS + hd16] + acol[src_e * NUM_HEADS + hd16];
    e = (e > 0.f) ? e : NEG_SLOPE * e;

    float m = e;
    #pragma unroll
    for (int off = 8; off >= 1; off >>= 1)
        m = fmaxf(m, __shfl_xor(m, off, 16));
    float ex = __expf(e - m);
    float s = ex;
    #pragma unroll
    for (int off = 8; off >= 1; off >>= 1)
        s += __shfl_xor(s, off, 16);
    float alpha = ex / s;            // alpha[head=hd16][edge=j16] at this lane

    // ---- Phase 2: wave w gathers edges 4w..4w+3, full rows, 4 feats/lane.
    // Lane l covers features 4l..4l+3; its head is l>>4; alpha source lane
    // for edge j is (l>>4)*16 + j.
    const int myHeadBase = (lane >> 4) << 4;
    float acc0 = 0.f, acc1 = 0.f, acc2 = 0.f, acc3 = 0.f;

    #pragma unroll
    for (int jj = 0; jj < 4; ++jj) {
        int j = wave * 4 + jj;
        int sj = __shfl(src_e, j, 64);                 // broadcast (uniform j)
        float a = __shfl(alpha, myHeadBase + j, 64);   // per-lane-group select
        uint2 v = *(const uint2*)&Hb[(size_t)sj * HF + lane * 4];
        acc0 = fmaf(a, bf2f((unsigned short)(v.x & 0xffffu)), acc0);
        acc1 = fmaf(a, bf2f((unsigned short)(v.x >> 16)),     acc1);
        acc2 = fmaf(a, bf2f((unsigned short)(v.y & 0xffffu)), acc2);
        acc3 = fmaf(a, bf2f((unsigned short)(v.y >> 16)),     acc3);
    }

    // ---- Phase 3: cross-wave reduce.
    red[wave][lane * 4 + 0] = acc0;
    red[wave][lane * 4 + 1] = acc1;
    red[wave][lane * 4 + 2] = acc2;
    red[wave][lane * 4 + 3] = acc3;
    __syncthreads();

    out[(size_t)n * HF + tid] =
        red[0][tid] + red[1][tid] + red[2][tid] + red[3][tid];
}

// ---------------------------------------------------------------------------
extern "C" void kernel_launch(void* const* d_in, const int* in_sizes, int n_in,
                              void* d_out, int out_size, void* d_ws, size_t ws_size,
                              hipStream_t stream) {
    // Inputs: row_ptr, col_ind, col_ptr, row_ind, feat, W, attn_l, attn_r
    const int*   col_ind = (const int*)  d_in[1];
    const float* feat    = (const float*)d_in[4];
    const float* W       = (const float*)d_in[5];
    const float* attn_l  = (const float*)d_in[6];
    const float* attn_r  = (const float*)d_in[7];
    float* out = (float*)d_out;

    const int N = in_sizes[0] - 1;   // 50000

    // Workspace: Hb bf16 [N*256] | arow f32 [N*4] | acol f32 [N*4] | Wt bf16 [64K]
    unsigned short* Hb = (unsigned short*)d_ws;
    float* arow = (float*)(Hb + (size_t)N * HF);
    float* acol = arow + (size_t)N * NUM_HEADS;
    unsigned short* Wt = (unsigned short*)(acol + (size_t)N * NUM_HEADS);

    conv_wt<<<256, 256, 0, stream>>>(W, Wt);

    dim3 ggrid((N + BM - 1) / BM);
    gat_gemm_mfma<<<ggrid, 256, 0, stream>>>(feat, Wt, attn_l, attn_r,
                                             Hb, arow, acol, N);

    gat_aggregate2<<<N, 256, 0, stream>>>(Hb, arow, acol, col_ind, out, N);
}

// Round 4
// 198.907 us; speedup vs baseline: 1.9069x; 1.0848x over previous
//
#include <hip/hip_runtime.h>
#include <hip/hip_bf16.h>

#define DEG        16
#define IN_FEATS   256
#define NUM_HEADS  4
#define OUT_FEATS  64
#define HF         256
#define NEG_SLOPE  0.2f

#define CPITCH 264     // 256 + 8 (epilogue store-transpose pitch)

typedef __attribute__((ext_vector_type(8))) short  short8;
typedef __attribute__((ext_vector_type(4))) float  floatx4;
typedef unsigned short ushortT;

__device__ __forceinline__ unsigned short f2bf(float f) {
    union { float f; unsigned u; } v; v.f = f;
    unsigned r = v.u + 0x7fffu + ((v.u >> 16) & 1u);   // round-to-nearest-even
    return (unsigned short)(r >> 16);
}
__device__ __forceinline__ float bf2f(unsigned short u) {
    union { unsigned u; float f; } v; v.u = ((unsigned)u) << 16;
    return v.f;
}
__device__ __forceinline__ unsigned pk2(float lo, float hi) {
    return (unsigned)f2bf(lo) | ((unsigned)f2bf(hi) << 16);
}

// async 16B global -> LDS (wave-uniform LDS base + lane*16)
__device__ __forceinline__ void load16_g2l(const void* g, void* lds) {
    __builtin_amdgcn_global_load_lds(
        (const __attribute__((address_space(1))) unsigned int*)(unsigned long long)g,
        (__attribute__((address_space(3))) unsigned int*)(unsigned int)(unsigned long long)lds,
        16, 0, 0);
}

// ---------------------------------------------------------------------------
// Kernel 0: prep.  Blocks [0,nfb): featb = bf16(feat) (8 elems/thread).
//           Blocks [nfb,nfb+256): Wt[n][k] = bf16(W[k][n]).
// ---------------------------------------------------------------------------
__global__ __launch_bounds__(256) void prep(
    const float* __restrict__ feat, const float* __restrict__ W,
    ushortT* __restrict__ featb, ushortT* __restrict__ Wt,
    int nfb, long long totalElems)
{
    int b = blockIdx.x;
    if (b < nfb) {
        long long base = (long long)b * 2048 + (long long)threadIdx.x * 8;
        if (base + 8 <= totalElems) {
            float4 v0 = *(const float4*)&feat[base];
            float4 v1 = *(const float4*)&feat[base + 4];
            uint4 o;
            o.x = pk2(v0.x, v0.y); o.y = pk2(v0.z, v0.w);
            o.z = pk2(v1.x, v1.y); o.w = pk2(v1.z, v1.w);
            *(uint4*)&featb[base] = o;
        }
    } else {
        int n = b - nfb;
        int k = threadIdx.x;
        Wt[n * 256 + k] = f2bf(W[k * 256 + n]);
    }
}

// ---------------------------------------------------------------------------
// Kernel 1: h = featb @ W via MFMA bf16.  Tile 64 rows x 256 cols, full K=256
// unrolled, ONE staging barrier.  A: async global_load_lds with XOR-swizzled
// source chunks (bank-conflict-free ds_read_b128).  B: direct global->VGPR
// per wave (L2-resident), 1-step prefetch.  Epilogue: fused attention scores
// + bf16 Hb store via LDS transpose (verified in rounds 2-3).
// ---------------------------------------------------------------------------
__global__ __launch_bounds__(256, 3) void gat_gemm_mfma2(
    const ushortT* __restrict__ featb,        // bf16 [M,256]
    const ushortT* __restrict__ Bt,           // Wt bf16 [n=256][k=256]
    const float* __restrict__ attn_l,         // [256]
    const float* __restrict__ attn_r,         // [256]
    ushortT* __restrict__ Hb,                 // h bf16 [M,256]
    float* __restrict__ arow,                 // [M,4]
    float* __restrict__ acol,                 // [M,4]
    int M)
{
    // As: 64 rows x 32 chunks x 16B = 32 KB (swizzled). Cs overlays (33.8 KB).
    __shared__ __align__(16) ushortT SMEM[64 * CPITCH];
    ushortT* As = SMEM;
    ushortT* Cs = SMEM;

    const int tid  = threadIdx.x;
    const int wave = tid >> 6;       // == head
    const int lane = tid & 63;
    const int l15  = lane & 15;
    const int quad = lane >> 4;
    const int rowBase = blockIdx.x * 64;

    // ---- Stage A: 2048 chunks of 16B, 8 async issues per thread.
    // Chunk slot s = wave*512 + t*64 + lane  ->  (row = s>>5, c_stored = s&31).
    // Slot holds global chunk c_g = c_stored ^ (row & 7)  (low-3-bit XOR).
    #pragma unroll
    for (int t = 0; t < 8; ++t) {
        int row  = wave * 16 + t * 2 + (lane >> 5);
        int cst  = lane & 31;
        int cg   = cst ^ (row & 7);                 // XOR touches low 3 bits only
        int grow = rowBase + row; if (grow > M - 1) grow = M - 1;
        const ushortT* g = featb + (long long)grow * 256 + cg * 8;
        load16_g2l(g, &As[(wave * 512 + t * 64) * 8]);
    }

    // ---- Prefetch B for ks=0 (independent of LDS; overlaps staging drain).
    short8 bbuf[2][4];
    #pragma unroll
    for (int ni = 0; ni < 4; ++ni)
        bbuf[0][ni] = *(const short8*)&Bt[(wave * 64 + ni * 16 + l15) * 256 + quad * 8];

    __syncthreads();   // drains the global_load_lds queue

    floatx4 acc[4][4] = {};

    #pragma unroll
    for (int ks = 0; ks < 8; ++ks) {
        if (ks < 7) {
            #pragma unroll
            for (int ni = 0; ni < 4; ++ni)
                bbuf[(ks + 1) & 1][ni] = *(const short8*)
                    &Bt[(wave * 64 + ni * 16 + l15) * 256 + (ks + 1) * 32 + quad * 8];
        }
        short8 af[4];
        #pragma unroll
        for (int mi = 0; mi < 4; ++mi) {
            int row = mi * 16 + l15;
            int q   = ks * 4 + quad;
            int cst = q ^ (row & 7);
            af[mi] = *(const short8*)&As[row * 256 + cst * 8];
        }
        #pragma unroll
        for (int mi = 0; mi < 4; ++mi)
            #pragma unroll
            for (int ni = 0; ni < 4; ++ni)
                acc[mi][ni] = __builtin_amdgcn_mfma_f32_16x16x32_bf16(
                    af[mi], bbuf[ks & 1][ni], acc[mi][ni], 0, 0, 0);
    }

    // ---- Epilogue A: attention scores (wave == head). No LDS use.
    float al[4], ar[4];
    #pragma unroll
    for (int ni = 0; ni < 4; ++ni) {
        al[ni] = attn_l[wave * 64 + ni * 16 + l15];
        ar[ni] = attn_r[wave * 64 + ni * 16 + l15];
    }
    #pragma unroll
    for (int mi = 0; mi < 4; ++mi) {
        #pragma unroll
        for (int reg = 0; reg < 4; ++reg) {
            float pl = 0.f, pr = 0.f;
            #pragma unroll
            for (int ni = 0; ni < 4; ++ni) {
                pl = fmaf(acc[mi][ni][reg], al[ni], pl);
                pr = fmaf(acc[mi][ni][reg], ar[ni], pr);
            }
            #pragma unroll
            for (int off = 8; off >= 1; off >>= 1) {
                pl += __shfl_xor(pl, off, 64);   // stays within 16-lane quad
                pr += __shfl_xor(pr, off, 64);
            }
            if (l15 == 0) {
                int gr = rowBase + mi * 16 + quad * 4 + reg;
                if (gr < M) {
                    arow[gr * NUM_HEADS + wave] = pl;
                    acol[gr * NUM_HEADS + wave] = pr;
                }
            }
        }
    }

    __syncthreads();   // all As reads complete before Cs overlay

    // ---- Epilogue B: h -> bf16, coalesced store via LDS transpose.
    #pragma unroll
    for (int mi = 0; mi < 4; ++mi)
        #pragma unroll
        for (int ni = 0; ni < 4; ++ni)
            #pragma unroll
            for (int reg = 0; reg < 4; ++reg)
                Cs[(mi * 16 + quad * 4 + reg) * CPITCH + wave * 64 + ni * 16 + l15] =
                    f2bf(acc[mi][ni][reg]);
    __syncthreads();

    #pragma unroll
    for (int i = 0; i < 8; ++i) {
        int f  = tid + 256 * i;
        int r  = f >> 5;
        int c8 = (f & 31) << 3;
        int gr = rowBase + r;
        if (gr < M) {
            uint4 v = *(const uint4*)&Cs[r * CPITCH + c8];
            *(uint4*)&Hb[(size_t)gr * HF + c8] = v;
        }
    }
}

// ---------------------------------------------------------------------------
// Kernel 2: per-dst softmax + gather, full-row 8B/lane loads (unchanged).
// ---------------------------------------------------------------------------
__global__ __launch_bounds__(256) void gat_aggregate2(
    const ushortT* __restrict__ Hb,          // bf16 [N,256]
    const float* __restrict__ arow,          // [N,4]
    const float* __restrict__ acol,          // [N,4]
    const int* __restrict__ col_ind,         // [N*16]
    float* __restrict__ out,                 // [N,256] fp32
    int N)
{
    __shared__ float red[4][256];

    const int n = blockIdx.x;
    const int tid  = threadIdx.x;
    const int wave = tid >> 6;
    const int lane = tid & 63;
    const int j16  = lane & 15;      // edge index for score phase
    const int hd16 = lane >> 4;      // head index for score phase

    int   src_e = col_ind[n * DEG + j16];
    float e = arow[n * NUM_HEADS + hd16] + acol[src_e * NUM_HEADS + hd16];
    e = (e > 0.f) ? e : NEG_SLOPE * e;

    float m = e;
    #pragma unroll
    for (int off = 8; off >= 1; off >>= 1)
        m = fmaxf(m, __shfl_xor(m, off, 16));
    float ex = __expf(e - m);
    float s = ex;
    #pragma unroll
    for (int off = 8; off >= 1; off >>= 1)
        s += __shfl_xor(s, off, 16);
    float alpha = ex / s;

    const int myHeadBase = (lane >> 4) << 4;
    float acc0 = 0.f, acc1 = 0.f, acc2 = 0.f, acc3 = 0.f;

    #pragma unroll
    for (int jj = 0; jj < 4; ++jj) {
        int j = wave * 4 + jj;
        int sj = __shfl(src_e, j, 64);
        float a = __shfl(alpha, myHeadBase + j, 64);
        uint2 v = *(const uint2*)&Hb[(size_t)sj * HF + lane * 4];
        acc0 = fmaf(a, bf2f((unsigned short)(v.x & 0xffffu)), acc0);
        acc1 = fmaf(a, bf2f((unsigned short)(v.x >> 16)),     acc1);
        acc2 = fmaf(a, bf2f((unsigned short)(v.y & 0xffffu)), acc2);
        acc3 = fmaf(a, bf2f((unsigned short)(v.y >> 16)),     acc3);
    }

    red[wave][lane * 4 + 0] = acc0;
    red[wave][lane * 4 + 1] = acc1;
    red[wave][lane * 4 + 2] = acc2;
    red[wave][lane * 4 + 3] = acc3;
    __syncthreads();

    out[(size_t)n * HF + tid] =
        red[0][tid] + red[1][tid] + red[2][tid] + red[3][tid];
}

// ---------------------------------------------------------------------------
extern "C" void kernel_launch(void* const* d_in, const int* in_sizes, int n_in,
                              void* d_out, int out_size, void* d_ws, size_t ws_size,
                              hipStream_t stream) {
    // Inputs: row_ptr, col_ind, col_ptr, row_ind, feat, W, attn_l, attn_r
    const int*   col_ind = (const int*)  d_in[1];
    const float* feat    = (const float*)d_in[4];
    const float* W       = (const float*)d_in[5];
    const float* attn_l  = (const float*)d_in[6];
    const float* attn_r  = (const float*)d_in[7];
    float* out = (float*)d_out;

    const int N = in_sizes[0] - 1;   // 50000

    // featb scratch lives in d_out (25.6 MB < 51.2 MB; aggregate rewrites all
    // of d_out afterwards).  ws: Hb bf16 | arow | acol | Wt  (= 27.3 MB).
    ushortT* featb = (ushortT*)d_out;
    ushortT* Hb    = (ushortT*)d_ws;
    float*   arow  = (float*)(Hb + (size_t)N * HF);
    float*   acol  = arow + (size_t)N * NUM_HEADS;
    ushortT* Wt    = (ushortT*)(acol + (size_t)N * NUM_HEADS);

    const long long totalElems = (long long)N * HF;
    const int nfb = (int)((totalElems + 2047) / 2048);

    prep<<<nfb + 256, 256, 0, stream>>>(feat, W, featb, Wt, nfb, totalElems);

    dim3 ggrid((N + 63) / 64);
    gat_gemm_mfma2<<<ggrid, 256, 0, stream>>>(featb, Wt, attn_l, attn_r,
                                              Hb, arow, acol, N);

    gat_aggregate2<<<N, 256, 0, stream>>>(Hb, arow, acol, col_ind, out, N);
}

// Round 5
// 198.595 us; speedup vs baseline: 1.9098x; 1.0016x over previous
//
#include <hip/hip_runtime.h>
#include <hip/hip_bf16.h>

#define DEG        16
#define IN_FEATS   256
#define NUM_HEADS  4
#define OUT_FEATS  64
#define HF         256
#define NEG_SLOPE  0.2f

#define CPITCH 264     // 256 + 8 (epilogue store-transpose pitch)

typedef __attribute__((ext_vector_type(8))) short  short8;
typedef __attribute__((ext_vector_type(4))) float  floatx4;
typedef unsigned short ushortT;

__device__ __forceinline__ unsigned short f2bf(float f) {
    union { float f; unsigned u; } v; v.f = f;
    unsigned r = v.u + 0x7fffu + ((v.u >> 16) & 1u);   // round-to-nearest-even
    return (unsigned short)(r >> 16);
}
__device__ __forceinline__ float bf2f(unsigned short u) {
    union { unsigned u; float f; } v; v.u = ((unsigned)u) << 16;
    return v.f;
}
__device__ __forceinline__ unsigned pk2(float lo, float hi) {
    return (unsigned)f2bf(lo) | ((unsigned)f2bf(hi) << 16);
}

// async 16B global -> LDS (wave-uniform LDS base + lane*16)
__device__ __forceinline__ void load16_g2l(const void* g, void* lds) {
    __builtin_amdgcn_global_load_lds(
        (const __attribute__((address_space(1))) unsigned int*)(unsigned long long)g,
        (__attribute__((address_space(3))) unsigned int*)(unsigned int)(unsigned long long)lds,
        16, 0, 0);
}

// ---------------------------------------------------------------------------
// Kernel 0: prep.  Blocks [0,nfb): featb = bf16(feat) (8 elems/thread).
//           Blocks [nfb,nfb+256): Wt[n][k] = bf16(W[k][n]).
// ---------------------------------------------------------------------------
__global__ __launch_bounds__(256) void prep(
    const float* __restrict__ feat, const float* __restrict__ W,
    ushortT* __restrict__ featb, ushortT* __restrict__ Wt,
    int nfb, long long totalElems)
{
    int b = blockIdx.x;
    if (b < nfb) {
        long long base = (long long)b * 2048 + (long long)threadIdx.x * 8;
        if (base + 8 <= totalElems) {
            float4 v0 = *(const float4*)&feat[base];
            float4 v1 = *(const float4*)&feat[base + 4];
            uint4 o;
            o.x = pk2(v0.x, v0.y); o.y = pk2(v0.z, v0.w);
            o.z = pk2(v1.x, v1.y); o.w = pk2(v1.z, v1.w);
            *(uint4*)&featb[base] = o;
        }
    } else {
        int n = b - nfb;
        int k = threadIdx.x;
        Wt[n * 256 + k] = f2bf(W[k * 256 + n]);
    }
}

// ---------------------------------------------------------------------------
// Kernel 1: h = featb @ W via MFMA bf16 (unchanged from round 4).
// ---------------------------------------------------------------------------
__global__ __launch_bounds__(256, 3) void gat_gemm_mfma2(
    const ushortT* __restrict__ featb,        // bf16 [M,256]
    const ushortT* __restrict__ Bt,           // Wt bf16 [n=256][k=256]
    const float* __restrict__ attn_l,         // [256]
    const float* __restrict__ attn_r,         // [256]
    ushortT* __restrict__ Hb,                 // h bf16 [M,256]
    float* __restrict__ arow,                 // [M,4]
    float* __restrict__ acol,                 // [M,4]
    int M)
{
    __shared__ __align__(16) ushortT SMEM[64 * CPITCH];
    ushortT* As = SMEM;
    ushortT* Cs = SMEM;

    const int tid  = threadIdx.x;
    const int wave = tid >> 6;       // == head
    const int lane = tid & 63;
    const int l15  = lane & 15;
    const int quad = lane >> 4;
    const int rowBase = blockIdx.x * 64;

    #pragma unroll
    for (int t = 0; t < 8; ++t) {
        int row  = wave * 16 + t * 2 + (lane >> 5);
        int cst  = lane & 31;
        int cg   = cst ^ (row & 7);
        int grow = rowBase + row; if (grow > M - 1) grow = M - 1;
        const ushortT* g = featb + (long long)grow * 256 + cg * 8;
        load16_g2l(g, &As[(wave * 512 + t * 64) * 8]);
    }

    short8 bbuf[2][4];
    #pragma unroll
    for (int ni = 0; ni < 4; ++ni)
        bbuf[0][ni] = *(const short8*)&Bt[(wave * 64 + ni * 16 + l15) * 256 + quad * 8];

    __syncthreads();

    floatx4 acc[4][4] = {};

    #pragma unroll
    for (int ks = 0; ks < 8; ++ks) {
        if (ks < 7) {
            #pragma unroll
            for (int ni = 0; ni < 4; ++ni)
                bbuf[(ks + 1) & 1][ni] = *(const short8*)
                    &Bt[(wave * 64 + ni * 16 + l15) * 256 + (ks + 1) * 32 + quad * 8];
        }
        short8 af[4];
        #pragma unroll
        for (int mi = 0; mi < 4; ++mi) {
            int row = mi * 16 + l15;
            int q   = ks * 4 + quad;
            int cst = q ^ (row & 7);
            af[mi] = *(const short8*)&As[row * 256 + cst * 8];
        }
        #pragma unroll
        for (int mi = 0; mi < 4; ++mi)
            #pragma unroll
            for (int ni = 0; ni < 4; ++ni)
                acc[mi][ni] = __builtin_amdgcn_mfma_f32_16x16x32_bf16(
                    af[mi], bbuf[ks & 1][ni], acc[mi][ni], 0, 0, 0);
    }

    float al[4], ar[4];
    #pragma unroll
    for (int ni = 0; ni < 4; ++ni) {
        al[ni] = attn_l[wave * 64 + ni * 16 + l15];
        ar[ni] = attn_r[wave * 64 + ni * 16 + l15];
    }
    #pragma unroll
    for (int mi = 0; mi < 4; ++mi) {
        #pragma unroll
        for (int reg = 0; reg < 4; ++reg) {
            float pl = 0.f, pr = 0.f;
            #pragma unroll
            for (int ni = 0; ni < 4; ++ni) {
                pl = fmaf(acc[mi][ni][reg], al[ni], pl);
                pr = fmaf(acc[mi][ni][reg], ar[ni], pr);
            }
            #pragma unroll
            for (int off = 8; off >= 1; off >>= 1) {
                pl += __shfl_xor(pl, off, 64);
                pr += __shfl_xor(pr, off, 64);
            }
            if (l15 == 0) {
                int gr = rowBase + mi * 16 + quad * 4 + reg;
                if (gr < M) {
                    arow[gr * NUM_HEADS + wave] = pl;
                    acol[gr * NUM_HEADS + wave] = pr;
                }
            }
        }
    }

    __syncthreads();

    #pragma unroll
    for (int mi = 0; mi < 4; ++mi)
        #pragma unroll
        for (int ni = 0; ni < 4; ++ni)
            #pragma unroll
            for (int reg = 0; reg < 4; ++reg)
                Cs[(mi * 16 + quad * 4 + reg) * CPITCH + wave * 64 + ni * 16 + l15] =
                    f2bf(acc[mi][ni][reg]);
    __syncthreads();

    #pragma unroll
    for (int i = 0; i < 8; ++i) {
        int f  = tid + 256 * i;
        int r  = f >> 5;
        int c8 = (f & 31) << 3;
        int gr = rowBase + r;
        if (gr < M) {
            uint4 v = *(const uint4*)&Cs[r * CPITCH + c8];
            *(uint4*)&Hb[(size_t)gr * HF + c8] = v;
        }
    }
}

// ---------------------------------------------------------------------------
// Kernel 2 (v3): ONE WAVE PER NODE. No LDS, no barriers.
// Score phase: lane = (head=lane>>4, edge=lane&15); width-16 shuffle softmax.
// Gather phase: lane l owns feats 4l..4l+3 (uint2 bf16); 16 full-row loads
// in flight per wave; alpha via bpermute, src via readlane. float4 store.
// ---------------------------------------------------------------------------
__global__ __launch_bounds__(256) void gat_aggregate3(
    const ushortT* __restrict__ Hb,          // bf16 [N,256]
    const float* __restrict__ arow,          // [N,4]
    const float* __restrict__ acol,          // [N,4]
    const int* __restrict__ col_ind,         // [N*16]
    float* __restrict__ out,                 // [N,256] fp32
    int N)
{
    const int tid  = threadIdx.x;
    const int wave = tid >> 6;
    const int lane = tid & 63;
    const int n    = blockIdx.x * 4 + wave;
    if (n >= N) return;

    const int j16  = lane & 15;
    const int hd16 = lane >> 4;

    // ---- scores: lane (hd16, j16) -> e[edge=j16][head=hd16]
    int   src_e = col_ind[n * DEG + j16];
    float e = arow[n * NUM_HEADS + hd16] + acol[src_e * NUM_HEADS + hd16];
    e = (e > 0.f) ? e : NEG_SLOPE * e;

    float m = e;
    #pragma unroll
    for (int off = 8; off >= 1; off >>= 1)
        m = fmaxf(m, __shfl_xor(m, off, 16));
    float ex = __expf(e - m);
    float s = ex;
    #pragma unroll
    for (int off = 8; off >= 1; off >>= 1)
        s += __shfl_xor(s, off, 16);
    float alpha = ex / s;                  // alpha[head=hd16][edge=j16]

    // ---- gather: 16 edges, full 512B rows, 4 feats per lane
    const int myHeadBase = (lane >> 4) << 4;   // == hd16*16 (head of feats 4l..4l+3)
    float acc0 = 0.f, acc1 = 0.f, acc2 = 0.f, acc3 = 0.f;

    #pragma unroll
    for (int j = 0; j < DEG; ++j) {
        int   sj = __shfl(src_e, j, 64);           // readlane (j literal)
        float a  = __shfl(alpha, myHeadBase + j, 64);  // bpermute
        uint2 v = *(const uint2*)&Hb[(size_t)sj * HF + lane * 4];
        acc0 = fmaf(a, bf2f((unsigned short)(v.x & 0xffffu)), acc0);
        acc1 = fmaf(a, bf2f((unsigned short)(v.x >> 16)),     acc1);
        acc2 = fmaf(a, bf2f((unsigned short)(v.y & 0xffffu)), acc2);
        acc3 = fmaf(a, bf2f((unsigned short)(v.y >> 16)),     acc3);
    }

    *(float4*)&out[(size_t)n * HF + lane * 4] = make_float4(acc0, acc1, acc2, acc3);
}

// ---------------------------------------------------------------------------
extern "C" void kernel_launch(void* const* d_in, const int* in_sizes, int n_in,
                              void* d_out, int out_size, void* d_ws, size_t ws_size,
                              hipStream_t stream) {
    // Inputs: row_ptr, col_ind, col_ptr, row_ind, feat, W, attn_l, attn_r
    const int*   col_ind = (const int*)  d_in[1];
    const float* feat    = (const float*)d_in[4];
    const float* W       = (const float*)d_in[5];
    const float* attn_l  = (const float*)d_in[6];
    const float* attn_r  = (const float*)d_in[7];
    float* out = (float*)d_out;

    const int N = in_sizes[0] - 1;   // 50000

    // featb scratch lives in d_out (25.6 MB < 51.2 MB; aggregate rewrites all
    // of d_out afterwards).  ws: Hb bf16 | arow | acol | Wt  (= 27.3 MB).
    ushortT* featb = (ushortT*)d_out;
    ushortT* Hb    = (ushortT*)d_ws;
    float*   arow  = (float*)(Hb + (size_t)N * HF);
    float*   acol  = arow + (size_t)N * NUM_HEADS;
    ushortT* Wt    = (ushortT*)(acol + (size_t)N * NUM_HEADS);

    const long long totalElems = (long long)N * HF;
    const int nfb = (int)((totalElems + 2047) / 2048);

    prep<<<nfb + 256, 256, 0, stream>>>(feat, W, featb, Wt, nfb, totalElems);

    dim3 ggrid((N + 63) / 64);
    gat_gemm_mfma2<<<ggrid, 256, 0, stream>>>(featb, Wt, attn_l, attn_r,
                                              Hb, arow, acol, N);

    gat_aggregate3<<<(N + 3) / 4, 256, 0, stream>>>(Hb, arow, acol, col_ind, out, N);
}